// Round 2
// baseline (2000.465 us; speedup 1.0000x reference)
//
#include <hip/hip_runtime.h>
#include <hip/hip_bf16.h>
#include <math.h>

#define NREL 8
#define LN_EPS 1e-5f
#define NEG_SLOPE 0.2f

typedef __hip_bfloat16 bf16;

__device__ __forceinline__ float b2f(const bf16 v) { return __bfloat162float(v); }
__device__ __forceinline__ unsigned short f2bu(float v) {
    bf16 t = __float2bfloat16(v);
    return *reinterpret_cast<unsigned short*>(&t);
}

__device__ __forceinline__ float4 load4(const float* p) { return *(const float4*)p; }
__device__ __forceinline__ float4 load4(const bf16* p) {
    ushort4 u = *(const ushort4*)p;
    union { unsigned int i; float f; } a, b, c, d;
    a.i = (unsigned int)u.x << 16;
    b.i = (unsigned int)u.y << 16;
    c.i = (unsigned int)u.z << 16;
    d.i = (unsigned int)u.w << 16;
    return make_float4(a.f, b.f, c.f, d.f);
}

// ---------------------------------------------------------------------------
// CSR build: count -> scan -> fill
// ---------------------------------------------------------------------------
__global__ __launch_bounds__(256) void count_kernel(const int* __restrict__ dst,
                                                    int* __restrict__ cnt, int E) {
    int e = blockIdx.x * 256 + threadIdx.x;
    if (e < E) atomicAdd(&cnt[dst[e]], 1);
}

__global__ __launch_bounds__(1024) void scan_kernel(const int* __restrict__ cnt,
                                                    int* __restrict__ rowptr, int N) {
    __shared__ int sm[1024];
    __shared__ int carry_s;
    int tid = threadIdx.x;
    if (tid == 0) { carry_s = 0; rowptr[0] = 0; }
    __syncthreads();
    for (int base = 0; base < N; base += 1024) {
        int v = (base + tid < N) ? cnt[base + tid] : 0;
        sm[tid] = v;
        __syncthreads();
        for (int off = 1; off < 1024; off <<= 1) {
            int t = (tid >= off) ? sm[tid - off] : 0;
            __syncthreads();
            sm[tid] += t;
            __syncthreads();
        }
        int incl = sm[tid];
        int carry = carry_s;
        if (base + tid < N) rowptr[base + tid + 1] = carry + incl;
        __syncthreads();
        if (tid == 1023) carry_s = carry + incl;
        __syncthreads();
    }
}

__global__ __launch_bounds__(256) void fill_kernel(const int* __restrict__ dst,
                                                   const int* __restrict__ rowptr,
                                                   int* __restrict__ cursor,
                                                   int* __restrict__ eids, int E) {
    int e = blockIdx.x * 256 + threadIdx.x;
    if (e < E) {
        int d = dst[e];
        int pos = atomicAdd(&cursor[d], 1);
        eids[rowptr[d] + pos] = e;
    }
}

// ---------------------------------------------------------------------------
// fp32-accumulate tiled GEMM, A is fp32 or bf16, W fp32, C out bf16.
// C[(m*NREL + r)*D + n] = sum_k A[m*K+k] * W[r*K*D + k*D + n]
// BM=BN=64, BK=32, 256 threads, 4x4 micro-tile.
// ---------------------------------------------------------------------------
template <typename AT>
__global__ __launch_bounds__(256) void gemm_kernel(const AT* __restrict__ A,
                                                   const float* __restrict__ W,
                                                   bf16* __restrict__ C,
                                                   int M, int K, int D) {
    const int r  = blockIdx.z;
    const int m0 = blockIdx.x * 64;
    const int n0 = blockIdx.y * 64;
    const float* B = W + (size_t)r * K * D;

    __shared__ float As[32][68];  // [k][m]
    __shared__ float Bs[32][64];  // [k][n]

    const int tid = threadIdx.x;
    const int tx = tid & 15;
    const int ty = tid >> 4;

    const int arow = tid >> 3;        // 0..31
    const int acol = (tid & 7) * 4;   // 0..28
    const int brow = tid >> 4;        // 0..15
    const int bcol = (tid & 15) * 4;  // 0..60

    float acc[4][4];
#pragma unroll
    for (int i = 0; i < 4; i++)
#pragma unroll
        for (int j = 0; j < 4; j++) acc[i][j] = 0.f;

    for (int k0 = 0; k0 < K; k0 += 32) {
#pragma unroll
        for (int half = 0; half < 2; half++) {
            int m = m0 + arow + half * 32;
            float4 av = make_float4(0.f, 0.f, 0.f, 0.f);
            if (m < M) av = load4(&A[(size_t)m * K + k0 + acol]);
            As[acol + 0][arow + half * 32] = av.x;
            As[acol + 1][arow + half * 32] = av.y;
            As[acol + 2][arow + half * 32] = av.z;
            As[acol + 3][arow + half * 32] = av.w;
        }
#pragma unroll
        for (int half = 0; half < 2; half++) {
            int k = k0 + brow + half * 16;
            *(float4*)&Bs[brow + half * 16][bcol] =
                *(const float4*)&B[(size_t)k * D + n0 + bcol];
        }
        __syncthreads();
#pragma unroll
        for (int k = 0; k < 32; k++) {
            float4 a4 = *(const float4*)&As[k][ty * 4];
            float4 b4 = *(const float4*)&Bs[k][tx * 4];
            float av[4] = {a4.x, a4.y, a4.z, a4.w};
            float bv[4] = {b4.x, b4.y, b4.z, b4.w};
#pragma unroll
            for (int i = 0; i < 4; i++)
#pragma unroll
                for (int j = 0; j < 4; j++)
                    acc[i][j] = fmaf(av[i], bv[j], acc[i][j]);
        }
        __syncthreads();
    }

#pragma unroll
    for (int i = 0; i < 4; i++) {
        int m = m0 + ty * 4 + i;
        if (m < M) {
            ushort4 cv = make_ushort4(f2bu(acc[i][0]), f2bu(acc[i][1]),
                                      f2bu(acc[i][2]), f2bu(acc[i][3]));
            *(ushort4*)&C[((size_t)m * NREL + r) * D + n0 + tx * 4] = cv;
        }
    }
}

// ---------------------------------------------------------------------------
// s[n,r,h] = sum_c xw[n,r,h*C+c]*a_src[h,c];  d likewise. One wave per (n,r).
// ---------------------------------------------------------------------------
template <int H, int C>
__global__ __launch_bounds__(256) void sd_kernel(const bf16* __restrict__ xw,
                                                 const float* __restrict__ asrc,
                                                 const float* __restrict__ adst,
                                                 float* __restrict__ sb,
                                                 float* __restrict__ db, int NR) {
    constexpr int D = H * C;
    constexpr int VPL = D / 64;
    constexpr int G = 64 / H;  // lanes per head group
    int wave = threadIdx.x >> 6;
    int lane = threadIdx.x & 63;
    int pair = blockIdx.x * 4 + wave;
    if (pair >= NR) return;
    const bf16* row = xw + (size_t)pair * D;
    int c0 = lane * VPL;
    float ps = 0.f, pd = 0.f;
    if constexpr (VPL == 4) {
        float4 v = load4(row + c0);
        float va[4] = {v.x, v.y, v.z, v.w};
#pragma unroll
        for (int k = 0; k < 4; k++) {
            ps = fmaf(va[k], asrc[c0 + k], ps);
            pd = fmaf(va[k], adst[c0 + k], pd);
        }
    } else {
        float v = b2f(row[c0]);
        ps = v * asrc[c0];
        pd = v * adst[c0];
    }
#pragma unroll
    for (int off = 1; off < G; off <<= 1) {
        ps += __shfl_xor(ps, off, 64);
        pd += __shfl_xor(pd, off, 64);
    }
    if ((lane & (G - 1)) == 0) {
        int h = c0 / C;
        sb[(size_t)pair * H + h] = ps;
        db[(size_t)pair * H + h] = pd;
    }
}

// ---------------------------------------------------------------------------
// Fused attention softmax + aggregation + bias (+ LayerNorm + ELU).
// One wave per destination node. 2-pass softmax over its edge list.
// ---------------------------------------------------------------------------
template <int H, int C, bool LNELU, typename OT>
__global__ __launch_bounds__(256) void agg_kernel(
    const int* __restrict__ rowptr, const int* __restrict__ eids,
    const int* __restrict__ srcs, const int* __restrict__ ets,
    const bf16* __restrict__ xw, const float* __restrict__ sb,
    const float* __restrict__ db, const float* __restrict__ ar,
    const float* __restrict__ bias, const float* __restrict__ gamma,
    const float* __restrict__ beta, OT* __restrict__ out, int N) {
    constexpr int D = H * C;
    constexpr int VPL = D / 64;
    int wave = threadIdx.x >> 6;
    int lane = threadIdx.x & 63;
    int n = blockIdx.x * 4 + wave;
    if (n >= N) return;
    int e0 = rowptr[n], e1 = rowptr[n + 1];
    int c0 = lane * VPL;
    int hl = c0 / C;

    // pass 1: max of leaky-relu logits per head
    float mx[H];
#pragma unroll
    for (int h = 0; h < H; h++) mx[h] = -1e30f;
    for (int base = e0; base < e1; base += 64) {
        int e = base + lane;
        if (e < e1) {
            int id = eids[e];
            int sj = srcs[id], t = ets[id];
            const float* sp = sb + ((size_t)sj * NREL + t) * H;
            const float* dp = db + ((size_t)n * NREL + t) * H;
            const float* ap = ar + t * H;
#pragma unroll
            for (int h = 0; h < H; h++) {
                float lg = sp[h] + dp[h] + ap[h];
                lg = lg > 0.f ? lg : NEG_SLOPE * lg;
                mx[h] = fmaxf(mx[h], lg);
            }
        }
    }
#pragma unroll
    for (int h = 0; h < H; h++)
#pragma unroll
        for (int off = 32; off; off >>= 1)
            mx[h] = fmaxf(mx[h], __shfl_xor(mx[h], off, 64));

    // pass 2: exp weights, denominator, weighted feature accumulation
    float acc[VPL];
#pragma unroll
    for (int k = 0; k < VPL; k++) acc[k] = 0.f;
    float den[H];
#pragma unroll
    for (int h = 0; h < H; h++) den[h] = 0.f;

    for (int base = e0; base < e1; base += 64) {
        int e = base + lane;
        float exh[H];
#pragma unroll
        for (int h = 0; h < H; h++) exh[h] = 0.f;
        int sj = 0, t = 0;
        if (e < e1) {
            int id = eids[e];
            sj = srcs[id];
            t = ets[id];
            const float* sp = sb + ((size_t)sj * NREL + t) * H;
            const float* dp = db + ((size_t)n * NREL + t) * H;
            const float* ap = ar + t * H;
#pragma unroll
            for (int h = 0; h < H; h++) {
                float lg = sp[h] + dp[h] + ap[h];
                lg = lg > 0.f ? lg : NEG_SLOPE * lg;
                exh[h] = __expf(lg - mx[h]);
                den[h] += exh[h];
            }
        }
        int cnt = min(64, e1 - base);
        for (int j = 0; j < cnt; j++) {
            int sjj = __shfl(sj, j, 64);
            int tj  = __shfl(t, j, 64);
            float w;
            if (H == 4) {
                float w0 = __shfl(exh[0], j, 64);
                float w1 = __shfl(exh[1], j, 64);
                float w2 = __shfl(exh[2], j, 64);
                float w3 = __shfl(exh[3], j, 64);
                w = (hl == 0) ? w0 : (hl == 1) ? w1 : (hl == 2) ? w2 : w3;
            } else {
                w = __shfl(exh[0], j, 64);
            }
            const bf16* xp = xw + ((size_t)sjj * NREL + tj) * D + c0;
            if (VPL == 4) {
                float4 v = load4(xp);
                acc[0] = fmaf(w, v.x, acc[0]);
                acc[1] = fmaf(w, v.y, acc[1]);
                acc[2] = fmaf(w, v.z, acc[2]);
                acc[3] = fmaf(w, v.w, acc[3]);
            } else {
                acc[0] = fmaf(w, b2f(xp[0]), acc[0]);
            }
        }
    }
#pragma unroll
    for (int h = 0; h < H; h++)
#pragma unroll
        for (int off = 32; off; off >>= 1) den[h] += __shfl_xor(den[h], off, 64);

    float dh = (H == 4) ? ((hl == 0) ? den[0] : (hl == 1) ? den[1]
                         : (hl == 2) ? den[2] : den[3])
                        : den[0];
    float inv = (e1 > e0) ? 1.f / dh : 0.f;

    float o[VPL];
#pragma unroll
    for (int k = 0; k < VPL; k++) o[k] = acc[k] * inv + bias[c0 + k];

    if constexpr (LNELU) {
        float sum = 0.f, sq = 0.f;
#pragma unroll
        for (int k = 0; k < VPL; k++) { sum += o[k]; sq += o[k] * o[k]; }
#pragma unroll
        for (int off = 32; off; off >>= 1) {
            sum += __shfl_xor(sum, off, 64);
            sq  += __shfl_xor(sq, off, 64);
        }
        float mean = sum / (float)D;
        float var = sq / (float)D - mean * mean;
        float rstd = rsqrtf(var + LN_EPS);
#pragma unroll
        for (int k = 0; k < VPL; k++) {
            float y = gamma[c0 + k] * (o[k] - mean) * rstd + beta[c0 + k];
            o[k] = y > 0.f ? y : expm1f(y);
        }
    }

    if constexpr (VPL == 4) {
        if constexpr (sizeof(OT) == 2) {
            ushort4 cv = make_ushort4(f2bu(o[0]), f2bu(o[1]), f2bu(o[2]), f2bu(o[3]));
            *(ushort4*)&out[(size_t)n * D + c0] = cv;
        } else {
            *(float4*)&out[(size_t)n * D + c0] = make_float4(o[0], o[1], o[2], o[3]);
        }
    } else {
        out[(size_t)n * D + c0] = (OT)o[0];
    }
}

// ---------------------------------------------------------------------------
extern "C" void kernel_launch(void* const* d_in, const int* in_sizes, int n_in,
                              void* d_out, int out_size, void* d_ws, size_t ws_size,
                              hipStream_t stream) {
    const float* x   = (const float*)d_in[0];
    const int* eidx  = (const int*)d_in[1];
    const int* etyp  = (const int*)d_in[2];
    const float* W0  = (const float*)d_in[3];
    const float* as0 = (const float*)d_in[4];
    const float* ad0 = (const float*)d_in[5];
    const float* ar0 = (const float*)d_in[6];
    const float* bi0 = (const float*)d_in[7];
    const float* W1  = (const float*)d_in[8];
    const float* as1 = (const float*)d_in[9];
    const float* ad1 = (const float*)d_in[10];
    const float* ar1 = (const float*)d_in[11];
    const float* bi1 = (const float*)d_in[12];
    const float* W2  = (const float*)d_in[13];
    const float* as2 = (const float*)d_in[14];
    const float* ad2 = (const float*)d_in[15];
    const float* ar2 = (const float*)d_in[16];
    const float* bi2 = (const float*)d_in[17];
    const float* g0  = (const float*)d_in[18];
    const float* be0 = (const float*)d_in[19];
    const float* g1  = (const float*)d_in[20];
    const float* be1 = (const float*)d_in[21];

    const int E = in_sizes[2];
    const int N = in_sizes[0] / 128;

    // workspace layout (bf16 bulk buffers; ~247 MB total)
    size_t off = 0;
    char* wsb = (char*)d_ws;
    auto alloc = [&](size_t bytes) -> void* {
        void* p = wsb + off;
        off += (bytes + 255) & ~(size_t)255;
        return p;
    };
    bf16* xw    = (bf16*)alloc((size_t)N * NREL * 256 * sizeof(bf16));
    bf16* h     = (bf16*)alloc((size_t)N * 256 * sizeof(bf16));
    float* sb   = (float*)alloc((size_t)N * NREL * 4 * sizeof(float));
    float* db   = (float*)alloc((size_t)N * NREL * 4 * sizeof(float));
    int* cnt    = (int*)alloc((size_t)N * sizeof(int));
    int* rowptr = (int*)alloc((size_t)(N + 1) * sizeof(int));
    int* eids   = (int*)alloc((size_t)E * sizeof(int));

    const int* srcs = eidx;
    const int* dsts = eidx + E;

    // CSR build
    hipMemsetAsync(cnt, 0, N * sizeof(int), stream);
    count_kernel<<<(E + 255) / 256, 256, 0, stream>>>(dsts, cnt, E);
    scan_kernel<<<1, 1024, 0, stream>>>(cnt, rowptr, N);
    hipMemsetAsync(cnt, 0, N * sizeof(int), stream);
    fill_kernel<<<(E + 255) / 256, 256, 0, stream>>>(dsts, rowptr, cnt, eids, E);

    const int NR = N * NREL;
    dim3 gGrid0((N + 63) / 64, 4, NREL);
    dim3 gGrid2((N + 63) / 64, 1, NREL);

    // layer 0: in=128 -> D=256, heads=4, LN+ELU
    gemm_kernel<float><<<gGrid0, 256, 0, stream>>>(x, W0, xw, N, 128, 256);
    sd_kernel<4, 64><<<(NR + 3) / 4, 256, 0, stream>>>(xw, as0, ad0, sb, db, NR);
    agg_kernel<4, 64, true, bf16><<<(N + 3) / 4, 256, 0, stream>>>(
        rowptr, eids, srcs, etyp, xw, sb, db, ar0, bi0, g0, be0, h, N);

    // layer 1: in=256 -> D=256, heads=4, LN+ELU
    gemm_kernel<bf16><<<gGrid0, 256, 0, stream>>>(h, W1, xw, N, 256, 256);
    sd_kernel<4, 64><<<(NR + 3) / 4, 256, 0, stream>>>(xw, as1, ad1, sb, db, NR);
    agg_kernel<4, 64, true, bf16><<<(N + 3) / 4, 256, 0, stream>>>(
        rowptr, eids, srcs, etyp, xw, sb, db, ar1, bi1, g1, be1, h, N);

    // layer 2: in=256 -> D=64, heads=1, no LN/ELU, fp32 output
    gemm_kernel<bf16><<<gGrid2, 256, 0, stream>>>(h, W2, xw, N, 256, 64);
    sd_kernel<1, 64><<<(NR + 3) / 4, 256, 0, stream>>>(xw, as2, ad2, sb, db, NR);
    agg_kernel<1, 64, false, float><<<(N + 3) / 4, 256, 0, stream>>>(
        rowptr, eids, srcs, etyp, xw, sb, db, ar2, bi2, nullptr, nullptr,
        (float*)d_out, N);
}

// Round 3
// 1028.514 us; speedup vs baseline: 1.9450x; 1.9450x over previous
//
#include <hip/hip_runtime.h>
#include <hip/hip_bf16.h>
#include <math.h>

#define NREL 8
#define LN_EPS 1e-5f
#define NEG_SLOPE 0.2f

typedef __hip_bfloat16 bf16;
typedef __attribute__((ext_vector_type(8))) short short8;
typedef __attribute__((ext_vector_type(4))) float floatx4;

__device__ __forceinline__ float b2f(const bf16 v) { return __bfloat162float(v); }
__device__ __forceinline__ float b2f(const float v) { return v; }
__device__ __forceinline__ unsigned short f2bu(float v) {
    bf16 t = __float2bfloat16(v);
    return *reinterpret_cast<unsigned short*>(&t);
}

__device__ __forceinline__ float4 load4(const float* p) { return *(const float4*)p; }
__device__ __forceinline__ float4 load4(const bf16* p) {
    ushort4 u = *(const ushort4*)p;
    union { unsigned int i; float f; } a, b, c, d;
    a.i = (unsigned int)u.x << 16;
    b.i = (unsigned int)u.y << 16;
    c.i = (unsigned int)u.z << 16;
    d.i = (unsigned int)u.w << 16;
    return make_float4(a.f, b.f, c.f, d.f);
}

__device__ __forceinline__ void async16(const void* g, void* l) {
    __builtin_amdgcn_global_load_lds(
        (const __attribute__((address_space(1))) void*)g,
        (__attribute__((address_space(3))) void*)l, 16, 0, 0);
}

// ---------------------------------------------------------------------------
// CSR build: count -> scan -> fill
// ---------------------------------------------------------------------------
__global__ __launch_bounds__(256) void count_kernel(const int* __restrict__ dst,
                                                    int* __restrict__ cnt, int E) {
    int e = blockIdx.x * 256 + threadIdx.x;
    if (e < E) atomicAdd(&cnt[dst[e]], 1);
}

__global__ __launch_bounds__(1024) void scan_kernel(const int* __restrict__ cnt,
                                                    int* __restrict__ rowptr, int N) {
    __shared__ int sm[1024];
    __shared__ int carry_s;
    int tid = threadIdx.x;
    if (tid == 0) { carry_s = 0; rowptr[0] = 0; }
    __syncthreads();
    for (int base = 0; base < N; base += 1024) {
        int v = (base + tid < N) ? cnt[base + tid] : 0;
        sm[tid] = v;
        __syncthreads();
        for (int off = 1; off < 1024; off <<= 1) {
            int t = (tid >= off) ? sm[tid - off] : 0;
            __syncthreads();
            sm[tid] += t;
            __syncthreads();
        }
        int incl = sm[tid];
        int carry = carry_s;
        if (base + tid < N) rowptr[base + tid + 1] = carry + incl;
        __syncthreads();
        if (tid == 1023) carry_s = carry + incl;
        __syncthreads();
    }
}

__global__ __launch_bounds__(256) void fill_kernel(const int* __restrict__ dst,
                                                   const int* __restrict__ rowptr,
                                                   int* __restrict__ cursor,
                                                   int* __restrict__ eids, int E) {
    int e = blockIdx.x * 256 + threadIdx.x;
    if (e < E) {
        int d = dst[e];
        int pos = atomicAdd(&cursor[d], 1);
        eids[rowptr[d] + pos] = e;
    }
}

// ---------------------------------------------------------------------------
// x fp32 -> bf16 (vectorized)
// ---------------------------------------------------------------------------
__global__ __launch_bounds__(256) void convx_kernel(const float* __restrict__ x,
                                                    bf16* __restrict__ xb, int total4) {
    int i = blockIdx.x * 256 + threadIdx.x;
    if (i < total4) {
        float4 v = ((const float4*)x)[i];
        ushort4 o = make_ushort4(f2bu(v.x), f2bu(v.y), f2bu(v.z), f2bu(v.w));
        ((ushort4*)xb)[i] = o;
    }
}

// ---------------------------------------------------------------------------
// Pack W fp32 [R][K][Nc] into MFMA-B-fragment order, split hi/lo bf16:
// packed idx = ((((r*(K/32)+kt)*4 + q)*(Nc/16) + nt)*16 + nl)*8 + kk
// value = W[r][kt*32 + q*8 + kk][nt*16 + nl]
// ---------------------------------------------------------------------------
__global__ __launch_bounds__(256) void packw_kernel(const float* __restrict__ W,
                                                    bf16* __restrict__ hi,
                                                    bf16* __restrict__ lo,
                                                    int K, int Nc, int total) {
    int i = blockIdx.x * 256 + threadIdx.x;
    if (i >= total) return;
    int kk = i & 7;
    int t1 = i >> 3;
    int nl = t1 & 15;
    int t2 = t1 >> 4;
    int nt = t2 % (Nc / 16);
    int t3 = t2 / (Nc / 16);
    int q = t3 & 3;
    int t4 = t3 >> 2;
    int kt = t4 % (K / 32);
    int r = t4 / (K / 32);
    int k = kt * 32 + q * 8 + kk;
    int n = nt * 16 + nl;
    float w = W[((size_t)r * K + k) * Nc + n];
    bf16 h = __float2bfloat16(w);
    float rem = w - __bfloat162float(h);
    hi[i] = h;
    lo[i] = __float2bfloat16(rem);
}

// ---------------------------------------------------------------------------
// MFMA GEMM: C[(m*NREL+r)*Nc + n] = sum_k A[m*K+k] * (Whi+Wlo)[r][k][n]
// BM=128, BN in {128,64}. 4 waves in 2x2 (wm 64, wn BN/2).
// A staged in fragment order via global_load_lds gather; B pre-packed.
// ---------------------------------------------------------------------------
template <int BN, typename CT>
__global__ __launch_bounds__(256) void mfma_gemm(const bf16* __restrict__ A,
                                                 const bf16* __restrict__ Bh,
                                                 const bf16* __restrict__ Bl,
                                                 CT* __restrict__ C,
                                                 int M, int K, int Nc) {
    const int r = blockIdx.z;
    const int m0 = blockIdx.x * 128;
    const int n0 = blockIdx.y * BN;
    const int tid = threadIdx.x;
    const int wv = tid >> 6;
    const int lane = tid & 63;

    __shared__ __align__(16) short lsA[4096];      // 8 KB: [half][i][q][ml] x 8
    __shared__ __align__(16) short lsBh[BN * 32];  // [q][ntl][nl] x 8
    __shared__ __align__(16) short lsBl[BN * 32];

    const int wm0 = (wv & 1) * 64;
    const int wn0 = (wv >> 1) * (BN / 2);
    constexpr int JT = BN / 32;

    floatx4 acc[4][JT];
#pragma unroll
    for (int i = 0; i < 4; i++)
#pragma unroll
        for (int j = 0; j < JT; j++) acc[i][j] = (floatx4)(0.f);

    const bf16* bh_r = Bh + (size_t)r * K * Nc;
    const bf16* bl_r = Bl + (size_t)r * K * Nc;
    const int nkt = K >> 5;

    for (int kt = 0; kt < nkt; kt++) {
        // stage A (8 KB, fragment order): unit = half*256 + i*64 + q*16 + ml
#pragma unroll
        for (int c = 0; c < 2; c++) {
            int idx = c * 256 + tid;
            int half = idx >> 8;
            int it = (idx >> 6) & 3;
            int q = (idx >> 4) & 3;
            int ml = idx & 15;
            int row = m0 + half * 64 + it * 16 + ml;
            row = row < M ? row : M - 1;
            async16(A + (size_t)row * K + kt * 32 + q * 8,
                    &lsA[(c * 256 + wv * 64) * 8]);
        }
        // stage B hi/lo (contiguous in packed layout)
#pragma unroll
        for (int c = 0; c < BN / 64; c++) {
            int idx = c * 256 + tid;  // 0 .. 4*BN-1
            int q = idx / BN;
            int rem = idx % BN;
            int nt = rem >> 4;
            int nl = rem & 15;
            size_t goff = (size_t)kt * 32 * Nc +
                          ((size_t)(q * (Nc / 16) + (n0 >> 4) + nt) * 16 + nl) * 8;
            async16(bh_r + goff, &lsBh[(c * 256 + wv * 64) * 8]);
            async16(bl_r + goff, &lsBl[(c * 256 + wv * 64) * 8]);
        }
        __syncthreads();  // compiler drains vmcnt before barrier

        short8 af[4];
#pragma unroll
        for (int i = 0; i < 4; i++)
            af[i] = *(const short8*)&lsA[(((wv & 1) * 4 + i) * 64 + lane) * 8];

#pragma unroll
        for (int j = 0; j < JT; j++) {
            int ntl = (wv >> 1) * JT + j;
            int boff = ((lane >> 4) * BN + ntl * 16 + (lane & 15)) * 8;
            short8 bh = *(const short8*)&lsBh[boff];
            short8 bl = *(const short8*)&lsBl[boff];
#pragma unroll
            for (int i = 0; i < 4; i++) {
                acc[i][j] = __builtin_amdgcn_mfma_f32_16x16x32_bf16(af[i], bh, acc[i][j], 0, 0, 0);
                acc[i][j] = __builtin_amdgcn_mfma_f32_16x16x32_bf16(af[i], bl, acc[i][j], 0, 0, 0);
            }
        }
        __syncthreads();
    }

    // epilogue: C/D layout col=lane&15, row=(lane>>4)*4+reg
    const int ml = lane & 15, mq = lane >> 4;
#pragma unroll
    for (int i = 0; i < 4; i++) {
#pragma unroll
        for (int j = 0; j < JT; j++) {
            int col = n0 + wn0 + j * 16 + ml;
#pragma unroll
            for (int reg = 0; reg < 4; reg++) {
                int m = m0 + wm0 + i * 16 + mq * 4 + reg;
                if (m < M) {
                    float v = acc[i][j][reg];
                    if constexpr (sizeof(CT) == 2)
                        C[((size_t)m * NREL + r) * Nc + col] = __float2bfloat16(v);
                    else
                        C[((size_t)m * NREL + r) * Nc + col] = v;
                }
            }
        }
    }
}

// ---------------------------------------------------------------------------
// s[n,r,h] = sum_c xw[n,r,h*C+c]*a_src[h,c];  d likewise. One wave per (n,r).
// ---------------------------------------------------------------------------
template <int H, int C, typename XT>
__global__ __launch_bounds__(256) void sd_kernel(const XT* __restrict__ xw,
                                                 const float* __restrict__ asrc,
                                                 const float* __restrict__ adst,
                                                 float* __restrict__ sb,
                                                 float* __restrict__ db, int NR) {
    constexpr int D = H * C;
    constexpr int VPL = D / 64;
    constexpr int G = 64 / H;
    int wave = threadIdx.x >> 6;
    int lane = threadIdx.x & 63;
    int pair = blockIdx.x * 4 + wave;
    if (pair >= NR) return;
    const XT* row = xw + (size_t)pair * D;
    int c0 = lane * VPL;
    float ps = 0.f, pd = 0.f;
    if constexpr (VPL == 4) {
        float4 v = load4(row + c0);
        float va[4] = {v.x, v.y, v.z, v.w};
#pragma unroll
        for (int k = 0; k < 4; k++) {
            ps = fmaf(va[k], asrc[c0 + k], ps);
            pd = fmaf(va[k], adst[c0 + k], pd);
        }
    } else {
        float v = b2f(row[c0]);
        ps = v * asrc[c0];
        pd = v * adst[c0];
    }
#pragma unroll
    for (int off = 1; off < G; off <<= 1) {
        ps += __shfl_xor(ps, off, 64);
        pd += __shfl_xor(pd, off, 64);
    }
    if ((lane & (G - 1)) == 0) {
        int h = c0 / C;
        sb[(size_t)pair * H + h] = ps;
        db[(size_t)pair * H + h] = pd;
    }
}

// ---------------------------------------------------------------------------
// Fused attention softmax + aggregation + bias (+ LayerNorm + ELU).
// One wave per destination node.
// ---------------------------------------------------------------------------
template <int H, int C, bool LNELU, typename XT, typename OT>
__global__ __launch_bounds__(256) void agg_kernel(
    const int* __restrict__ rowptr, const int* __restrict__ eids,
    const int* __restrict__ srcs, const int* __restrict__ ets,
    const XT* __restrict__ xw, const float* __restrict__ sb,
    const float* __restrict__ db, const float* __restrict__ ar,
    const float* __restrict__ bias, const float* __restrict__ gamma,
    const float* __restrict__ beta, OT* __restrict__ out, int N) {
    constexpr int D = H * C;
    constexpr int VPL = D / 64;
    int wave = threadIdx.x >> 6;
    int lane = threadIdx.x & 63;
    int n = blockIdx.x * 4 + wave;
    if (n >= N) return;
    int e0 = rowptr[n], e1 = rowptr[n + 1];
    int c0 = lane * VPL;
    int hl = c0 / C;

    float mx[H];
#pragma unroll
    for (int h = 0; h < H; h++) mx[h] = -1e30f;
    for (int base = e0; base < e1; base += 64) {
        int e = base + lane;
        if (e < e1) {
            int id = eids[e];
            int sj = srcs[id], t = ets[id];
            const float* sp = sb + ((size_t)sj * NREL + t) * H;
            const float* dp = db + ((size_t)n * NREL + t) * H;
            const float* ap = ar + t * H;
#pragma unroll
            for (int h = 0; h < H; h++) {
                float lg = sp[h] + dp[h] + ap[h];
                lg = lg > 0.f ? lg : NEG_SLOPE * lg;
                mx[h] = fmaxf(mx[h], lg);
            }
        }
    }
#pragma unroll
    for (int h = 0; h < H; h++)
#pragma unroll
        for (int off = 32; off; off >>= 1)
            mx[h] = fmaxf(mx[h], __shfl_xor(mx[h], off, 64));

    float acc[VPL];
#pragma unroll
    for (int k = 0; k < VPL; k++) acc[k] = 0.f;
    float den[H];
#pragma unroll
    for (int h = 0; h < H; h++) den[h] = 0.f;

    for (int base = e0; base < e1; base += 64) {
        int e = base + lane;
        float exh[H];
#pragma unroll
        for (int h = 0; h < H; h++) exh[h] = 0.f;
        int sj = 0, t = 0;
        if (e < e1) {
            int id = eids[e];
            sj = srcs[id];
            t = ets[id];
            const float* sp = sb + ((size_t)sj * NREL + t) * H;
            const float* dp = db + ((size_t)n * NREL + t) * H;
            const float* ap = ar + t * H;
#pragma unroll
            for (int h = 0; h < H; h++) {
                float lg = sp[h] + dp[h] + ap[h];
                lg = lg > 0.f ? lg : NEG_SLOPE * lg;
                exh[h] = __expf(lg - mx[h]);
                den[h] += exh[h];
            }
        }
        int cnt = min(64, e1 - base);
        for (int j = 0; j < cnt; j++) {
            int sjj = __shfl(sj, j, 64);
            int tj  = __shfl(t, j, 64);
            float w;
            if (H == 4) {
                float w0 = __shfl(exh[0], j, 64);
                float w1 = __shfl(exh[1], j, 64);
                float w2 = __shfl(exh[2], j, 64);
                float w3 = __shfl(exh[3], j, 64);
                w = (hl == 0) ? w0 : (hl == 1) ? w1 : (hl == 2) ? w2 : w3;
            } else {
                w = __shfl(exh[0], j, 64);
            }
            const XT* xp = xw + ((size_t)sjj * NREL + tj) * D + c0;
            if (VPL == 4) {
                float4 v = load4(xp);
                acc[0] = fmaf(w, v.x, acc[0]);
                acc[1] = fmaf(w, v.y, acc[1]);
                acc[2] = fmaf(w, v.z, acc[2]);
                acc[3] = fmaf(w, v.w, acc[3]);
            } else {
                acc[0] = fmaf(w, b2f(xp[0]), acc[0]);
            }
        }
    }
#pragma unroll
    for (int h = 0; h < H; h++)
#pragma unroll
        for (int off = 32; off; off >>= 1) den[h] += __shfl_xor(den[h], off, 64);

    float dh = (H == 4) ? ((hl == 0) ? den[0] : (hl == 1) ? den[1]
                         : (hl == 2) ? den[2] : den[3])
                        : den[0];
    float inv = (e1 > e0) ? 1.f / dh : 0.f;

    float o[VPL];
#pragma unroll
    for (int k = 0; k < VPL; k++) o[k] = acc[k] * inv + bias[c0 + k];

    if constexpr (LNELU) {
        float sum = 0.f, sq = 0.f;
#pragma unroll
        for (int k = 0; k < VPL; k++) { sum += o[k]; sq += o[k] * o[k]; }
#pragma unroll
        for (int off = 32; off; off >>= 1) {
            sum += __shfl_xor(sum, off, 64);
            sq  += __shfl_xor(sq, off, 64);
        }
        float mean = sum / (float)D;
        float var = sq / (float)D - mean * mean;
        float rstd = rsqrtf(var + LN_EPS);
#pragma unroll
        for (int k = 0; k < VPL; k++) {
            float y = gamma[c0 + k] * (o[k] - mean) * rstd + beta[c0 + k];
            o[k] = y > 0.f ? y : expm1f(y);
        }
    }

    if constexpr (VPL == 4) {
        if constexpr (sizeof(OT) == 2) {
            ushort4 cv = make_ushort4(f2bu(o[0]), f2bu(o[1]), f2bu(o[2]), f2bu(o[3]));
            *(ushort4*)&out[(size_t)n * D + c0] = cv;
        } else {
            *(float4*)&out[(size_t)n * D + c0] = make_float4(o[0], o[1], o[2], o[3]);
        }
    } else {
        out[(size_t)n * D + c0] = (OT)o[0];
    }
}

// ---------------------------------------------------------------------------
extern "C" void kernel_launch(void* const* d_in, const int* in_sizes, int n_in,
                              void* d_out, int out_size, void* d_ws, size_t ws_size,
                              hipStream_t stream) {
    const float* x   = (const float*)d_in[0];
    const int* eidx  = (const int*)d_in[1];
    const int* etyp  = (const int*)d_in[2];
    const float* W0  = (const float*)d_in[3];
    const float* as0 = (const float*)d_in[4];
    const float* ad0 = (const float*)d_in[5];
    const float* ar0 = (const float*)d_in[6];
    const float* bi0 = (const float*)d_in[7];
    const float* W1  = (const float*)d_in[8];
    const float* as1 = (const float*)d_in[9];
    const float* ad1 = (const float*)d_in[10];
    const float* ar1 = (const float*)d_in[11];
    const float* bi1 = (const float*)d_in[12];
    const float* W2  = (const float*)d_in[13];
    const float* as2 = (const float*)d_in[14];
    const float* ad2 = (const float*)d_in[15];
    const float* ar2 = (const float*)d_in[16];
    const float* bi2 = (const float*)d_in[17];
    const float* g0  = (const float*)d_in[18];
    const float* be0 = (const float*)d_in[19];
    const float* g1  = (const float*)d_in[20];
    const float* be1 = (const float*)d_in[21];

    const int E = in_sizes[2];
    const int N = in_sizes[0] / 128;

    // workspace layout (~251 MB)
    size_t off = 0;
    char* wsb = (char*)d_ws;
    auto alloc = [&](size_t bytes) -> void* {
        void* p = wsb + off;
        off += (bytes + 255) & ~(size_t)255;
        return p;
    };
    char* xw_region = (char*)alloc((size_t)N * NREL * 256 * sizeof(bf16));  // 204.8 MB
    bf16* xw   = (bf16*)xw_region;          // layers 0/1 view
    float* xw2 = (float*)xw_region;         // layer 2 fp32 view (102.4 MB, aliases)
    char* h_region = (char*)alloc((size_t)N * 256 * sizeof(bf16));          // 25.6 MB
    bf16* h  = (bf16*)h_region;
    bf16* xb = (bf16*)h_region;             // x bf16 (12.8 MB) aliases h: dead before h is written
    float* sb   = (float*)alloc((size_t)N * NREL * 4 * sizeof(float));
    float* db   = (float*)alloc((size_t)N * NREL * 4 * sizeof(float));
    int* cnt    = (int*)alloc((size_t)N * sizeof(int));
    int* rowptr = (int*)alloc((size_t)(N + 1) * sizeof(int));
    int* eids   = (int*)alloc((size_t)E * sizeof(int));
    const int szW0 = NREL * 128 * 256, szW1 = NREL * 256 * 256, szW2 = NREL * 256 * 64;
    bf16* Wh0 = (bf16*)alloc((size_t)szW0 * sizeof(bf16));
    bf16* Wl0 = (bf16*)alloc((size_t)szW0 * sizeof(bf16));
    bf16* Wh1 = (bf16*)alloc((size_t)szW1 * sizeof(bf16));
    bf16* Wl1 = (bf16*)alloc((size_t)szW1 * sizeof(bf16));
    bf16* Wh2 = (bf16*)alloc((size_t)szW2 * sizeof(bf16));
    bf16* Wl2 = (bf16*)alloc((size_t)szW2 * sizeof(bf16));

    const int* srcs = eidx;
    const int* dsts = eidx + E;

    // conversions / packing
    convx_kernel<<<(N * 128 / 4 + 255) / 256, 256, 0, stream>>>(x, xb, N * 128 / 4);
    packw_kernel<<<(szW0 + 255) / 256, 256, 0, stream>>>(W0, Wh0, Wl0, 128, 256, szW0);
    packw_kernel<<<(szW1 + 255) / 256, 256, 0, stream>>>(W1, Wh1, Wl1, 256, 256, szW1);
    packw_kernel<<<(szW2 + 255) / 256, 256, 0, stream>>>(W2, Wh2, Wl2, 256, 64, szW2);

    // CSR build
    hipMemsetAsync(cnt, 0, N * sizeof(int), stream);
    count_kernel<<<(E + 255) / 256, 256, 0, stream>>>(dsts, cnt, E);
    scan_kernel<<<1, 1024, 0, stream>>>(cnt, rowptr, N);
    hipMemsetAsync(cnt, 0, N * sizeof(int), stream);
    fill_kernel<<<(E + 255) / 256, 256, 0, stream>>>(dsts, rowptr, cnt, eids, E);

    const int NR = N * NREL;
    const int MB = (N + 127) / 128;

    // layer 0: in=128 -> D=256, heads=4, LN+ELU
    mfma_gemm<128, bf16><<<dim3(MB, 2, NREL), 256, 0, stream>>>(xb, Wh0, Wl0, xw, N, 128, 256);
    sd_kernel<4, 64, bf16><<<(NR + 3) / 4, 256, 0, stream>>>(xw, as0, ad0, sb, db, NR);
    agg_kernel<4, 64, true, bf16, bf16><<<(N + 3) / 4, 256, 0, stream>>>(
        rowptr, eids, srcs, etyp, xw, sb, db, ar0, bi0, g0, be0, h, N);

    // layer 1: in=256 -> D=256, heads=4, LN+ELU
    mfma_gemm<128, bf16><<<dim3(MB, 2, NREL), 256, 0, stream>>>(h, Wh1, Wl1, xw, N, 256, 256);
    sd_kernel<4, 64, bf16><<<(NR + 3) / 4, 256, 0, stream>>>(xw, as1, ad1, sb, db, NR);
    agg_kernel<4, 64, true, bf16, bf16><<<(N + 3) / 4, 256, 0, stream>>>(
        rowptr, eids, srcs, etyp, xw, sb, db, ar1, bi1, g1, be1, h, N);

    // layer 2: in=256 -> D=64, heads=1, fp32 xw, fp32 output
    mfma_gemm<64, float><<<dim3(MB, 1, NREL), 256, 0, stream>>>(h, Wh2, Wl2, xw2, N, 256, 64);
    sd_kernel<1, 64, float><<<(NR + 3) / 4, 256, 0, stream>>>(xw2, as2, ad2, sb, db, NR);
    agg_kernel<1, 64, false, float, float><<<(N + 3) / 4, 256, 0, stream>>>(
        rowptr, eids, srcs, etyp, xw2, sb, db, ar2, bi2, nullptr, nullptr,
        (float*)d_out, N);
}